// Round 8
// baseline (267.881 us; speedup 1.0000x reference)
//
#include <hip/hip_runtime.h>
#include <hip/hip_bf16.h>
#include <stdint.h>

typedef unsigned short u16;
typedef short s16x8 __attribute__((ext_vector_type(8)));
typedef float f32x4 __attribute__((ext_vector_type(4)));
typedef uint32_t u32x4 __attribute__((ext_vector_type(4)));

typedef const __attribute__((address_space(1))) void* gas_t;
typedef __attribute__((address_space(3))) void* las_t;

__device__ __forceinline__ uint32_t pack_bf16(float lo, float hi) {
  float2 f; f.x = lo; f.y = hi;
  __hip_bfloat162 h = __float22bfloat162_rn(f);
  union { __hip_bfloat162 h; uint32_t u; } c; c.h = h;
  return c.u;
}
__device__ __forceinline__ u16 f2bf(float f) {
  union { float f; uint32_t u; } a; a.f = f;
  uint32_t u = a.u;
  return (u16)((u + 0x7fffu + ((u >> 16) & 1u)) >> 16);
}
__device__ __forceinline__ float bf2f(uint32_t hbits) {
  union { uint32_t u; float f; } a; a.u = hbits << 16;
  return a.f;
}

__device__ __forceinline__ u32x4 bilin4(u32x4 q00, u32x4 q01, u32x4 q10, u32x4 q11,
                                        float w00, float w01, float w10, float w11) {
  u32x4 o;
#pragma unroll
  for (int k = 0; k < 4; ++k) {
    float lo = bf2f(q00[k] & 0xffff) * w00 + bf2f(q01[k] & 0xffff) * w01 +
               bf2f(q10[k] & 0xffff) * w10 + bf2f(q11[k] & 0xffff) * w11;
    float hi = bf2f(q00[k] >> 16) * w00 + bf2f(q01[k] >> 16) * w01 +
               bf2f(q10[k] >> 16) * w10 + bf2f(q11[k] >> 16) * w11;
    o[k] = pack_bf16(lo, hi);
  }
  return o;
}

// ---------------------------------------------------------------- fused prep
// Persistent double-buffered transpose (T3+T4: counted vmcnt, never drain).
// 768 persistent blocks (3/CU) x 512 thr; each loops ~7 sub-tiles of
// [48c x 128hw] f32 (24 KB) through 2 ping-pong LDS buffers. Per wave per
// sub-tile: 3 x global_load_lds (1 KB DMA). Steady state: issue next
// sub-tile's 3 loads -> s_waitcnt vmcnt(3) (current landed, next stays in
// flight ACROSS the barrier) -> raw s_barrier -> convert+store -> s_barrier
// -> flip. All 7 prior prep variants (rounds 2-7: 63-69 us invariant) shared
// a full vmcnt(0) drain per tile via __syncthreads; this removes it.
// jobs [0,2048): L1; [2048,2560): L2; [2560,2688): L3; [2688,2720): L4.
// bid [768,800): W convert+swizzle (grid-stride, unchanged).
//
// W layout: Wseed/Wpos in MFMA-fragment-linear order:
//   dWs[((nt*25 + kc)*64 + lid)*8 + e] = W[nt*16 + (lid&15)][kc*32 + (lid>>4)*8 + e]
__global__ __launch_bounds__(512, 6) void prep_all(
    const float* __restrict__ L1, const float* __restrict__ L2,
    const float* __restrict__ L3, const float* __restrict__ L4,
    const float* __restrict__ ws_w, const float* __restrict__ wp_w,
    u16* __restrict__ T1, u16* __restrict__ T2,
    u16* __restrict__ T3, u16* __restrict__ T4,
    u16* __restrict__ dWs, u16* __restrict__ dWp) {
  const int bid = blockIdx.x;
  const int t = threadIdx.x;

  if (bid >= 768) {  // ---- W convert: 159744 f32 total as 39936 float4s
    int t0 = (bid - 768) * 512 + t;
    for (int i = t0; i < 39936; i += 16384) {
      if (i < 38400) {
        int e4 = 4 * i;                 // element index in Wseed (n*800 + k)
        int n = e4 / 800;
        int k = e4 - n * 800;
        f32x4 v = *(const f32x4*)(ws_w + e4);
        int nt = n >> 4, mrow = n & 15;
        int kc = k >> 5, quad = (k >> 3) & 3, e0 = k & 7;  // e0 in {0,4}
        int dst = ((nt * 25 + kc) * 64 + (quad * 16 + mrow)) * 8 + e0;
        uint2 o;
        o.x = pack_bf16(v.x, v.y);
        o.y = pack_bf16(v.z, v.w);
        *(uint2*)(dWs + dst) = o;
      } else {
        int j = i - 38400;
        int e4 = 4 * j;                 // element index in Wpos (n*32 + k)
        int n = e4 >> 5, k = e4 & 31;
        f32x4 v = *(const f32x4*)(wp_w + e4);
        int nt = n >> 4, mrow = n & 15;
        int quad = k >> 3, e0 = k & 7;
        int dst = (nt * 64 + (quad * 16 + mrow)) * 8 + e0;
        uint2 o;
        o.x = pack_bf16(v.x, v.y);
        o.y = pack_bf16(v.z, v.w);
        *(uint2*)(dWp + dst) = o;
      }
    }
    return;
  }

  __shared__ __align__(16) float bufs[2][48 * 128];   // 2 x 24 KB

  const int l = t & 63, w = t >> 6;
  // 2720 jobs = 768*3 + 416: bid<416 -> 4 jobs, else 3. Sub-tiles = 2*jobs.
  const int nsub = ((bid < 416) ? 4 : 3) * 2;

  // ---- issue sub-tile m's 3 DMA loads into buf
  auto issue = [&](int m, float* buf) {
    int job = bid + (m >> 1) * 768;
    int s = m & 1;
    const float* src; int HW, tpl, rel;
    if (job < 2048)      { src = L1; HW = 16384; tpl = 256; rel = job; }
    else if (job < 2560) { src = L2; HW = 4096;  tpl = 64;  rel = job - 2048; }
    else if (job < 2688) { src = L3; HW = 1024;  tpl = 16;  rel = job - 2560; }
    else                 { src = L4; HW = 256;   tpl = 4;   rel = job - 2688; }
    int b = rel / tpl, r = rel % tpl;
    int hw0 = (r >> 1) * 128;
    int c0 = (r & 1) * 96 + 48 * s;
    const float* sb = src + ((size_t)b * 192 + c0) * HW + hw0;
#pragma unroll
    for (int i = 0; i < 3; ++i) {
      int k = w * 3 + i;                   // chunk: c rel rows 2k, 2k+1
      int crel = 2 * k + (l >> 5);
      int hwf = ((l & 31) << 2) ^ (((crel >> 3) & 7) << 2);  // global pre-swizzle
      __builtin_amdgcn_global_load_lds(
          (gas_t)(sb + (size_t)crel * HW + hwf),
          (las_t)(buf + k * 256),          // wave-uniform linear dest
          16, 0, 0);
    }
  };

  // ---- store sub-tile m from buf (LDS swizzled read -> bf16 -> 96B segs)
  auto store = [&](int m, const float* buf) {
    int job = bid + (m >> 1) * 768;
    int s = m & 1;
    u16* dst; int HW, tpl, rel;
    if (job < 2048)      { dst = T1; HW = 16384; tpl = 256; rel = job; }
    else if (job < 2560) { dst = T2; HW = 4096;  tpl = 64;  rel = job - 2048; }
    else if (job < 2688) { dst = T3; HW = 1024;  tpl = 16;  rel = job - 2560; }
    else                 { dst = T4; HW = 256;   tpl = 4;   rel = job - 2688; }
    int b = rel / tpl, r = rel % tpl;
    int hw0 = (r >> 1) * 128;
    int c0 = (r & 1) * 96 + 48 * s;
    uint32_t* d = (uint32_t*)(dst + ((size_t)b * HW + hw0) * 192) + (c0 >> 1);
#pragma unroll
    for (int i = 0; i < 3; ++i) {
      int e = i * 512 + t;                 // 1536 = 128 hw x 12 q2 (uint2)
      int hw = e / 12, q2 = e - hw * 12;   // consecutive q2 -> 96B contiguous
      float f0 = buf[(q2 * 4 + 0) * 128 + (hw ^ (((q2 * 4 + 0) >> 3) << 2))];
      float f1 = buf[(q2 * 4 + 1) * 128 + (hw ^ (((q2 * 4 + 1) >> 3) << 2))];
      float f2 = buf[(q2 * 4 + 2) * 128 + (hw ^ (((q2 * 4 + 2) >> 3) << 2))];
      float f3 = buf[(q2 * 4 + 3) * 128 + (hw ^ (((q2 * 4 + 3) >> 3) << 2))];
      uint2 v;
      v.x = pack_bf16(f0, f1);
      v.y = pack_bf16(f2, f3);
      *(uint2*)(d + hw * 96 + q2 * 2) = v;
    }
  };

  // ---- pipelined loop: load(m+1) in flight across store(m)'s barriers
  issue(0, bufs[0]);
  int cur = 0;
  for (int m = 0; m < nsub; ++m) {
    if (m + 1 < nsub) {
      issue(m + 1, bufs[cur ^ 1]);
      asm volatile("s_waitcnt vmcnt(3)" ::: "memory");  // m landed, m+1 in flight
    } else {
      asm volatile("s_waitcnt vmcnt(0)" ::: "memory");  // epilogue drain
    }
    __builtin_amdgcn_s_barrier();
    __builtin_amdgcn_sched_barrier(0);
    store(m, bufs[cur]);
    __builtin_amdgcn_s_barrier();          // protect buf reuse by m+2's DMA
    __builtin_amdgcn_sched_barrier(0);
    cur ^= 1;
  }
}

// ---------------------------------------------------------------- main fused
// 16 points/block, 2048 blocks, 256 threads (4 waves). xt [16][808] bf16 in
// LDS (25.9 KB -> 6 blocks/CU, 24 waves/CU). launch_bounds(256,6) caps VGPR
// at 85 so the deeper pipelines below don't cost occupancy.
__global__ __launch_bounds__(256, 6) void seed_main(
    const float* __restrict__ coords,
    const u16* __restrict__ T1, const u16* __restrict__ T2,
    const u16* __restrict__ T3, const u16* __restrict__ T4,
    const u16* __restrict__ Wseed, const u16* __restrict__ Wpos,
    const float* __restrict__ seed_b, const float* __restrict__ ln_g,
    const float* __restrict__ ln_b, const float* __restrict__ pos_b,
    float* __restrict__ out_seed, float* __restrict__ out_pos,
    float* __restrict__ out_cg) {

  __shared__ __align__(16) u16 xt[16 * 808];   // aliased later as preLN f32 [16][193]
  __shared__ float mu_s[16], rs_s[16];

  const int t = threadIdx.x;
  const int gp0 = blockIdx.x * 16;
  const int b = gp0 >> 12;

  // ---- center grid out
  if (t < 32) {
    int p = t >> 1, xy = t & 1;
    float c = coords[(gp0 + p) * 2 + xy];
    out_cg[(gp0 + p) * 2 + xy] = c * (2.0f / 511.0f) - 1.0f;
  }
  // ---- PE: 16 pts x 32 vals -> xt cols 768..799
  for (int i = 0; i < 2; ++i) {
    int e = i * 256 + t;
    int p = e >> 5, j = e & 31;
    float c = coords[(gp0 + p) * 2 + ((j >> 4) & 1)] * (1.0f / 512.0f);
    float v = c * (float)(1 << (j & 7));
    float a = (v - floorf(v)) * 6.283185307179586f;
    float r = (j & 8) ? __cosf(a) : __sinf(a);
    xt[p * 808 + 768 + j] = f2bf(r);
  }

  // ---- gather: thread owns one (p,lv); 6 chunks of 8 channels (16 B loads),
  // 2-deep software pipeline (prefetch chunk i+1 while interpolating chunk i).
  // Chunk phase rotated by lv so the 4 lv-lanes of a (p,c4b) group write
  // distinct LDS bank quads (kills the 4-way ds_write conflict).
  {
    const u16* B1 = T1 + (size_t)b * 16384 * 192;
    const u16* B2 = T2 + (size_t)b * 4096 * 192;
    const u16* B3 = T3 + (size_t)b * 1024 * 192;
    const u16* B4 = T4 + (size_t)b * 256 * 192;
    int plv = t >> 2;                  // [0,64)
    int lv = plv & 3, p = plv >> 2;
    int c4b = t & 3;                   // chunk phase
    float cx = coords[(gp0 + p) * 2 + 0];
    float cy = coords[(gp0 + p) * 2 + 1];
    float gx = cx * (2.0f / 511.0f) - 1.0f;
    float gy = cy * (2.0f / 511.0f) - 1.0f;
    int Wl = 128 >> lv;
    float ix = (gx + 1.0f) * 0.5f * (float)(Wl - 1);
    float iy = (gy + 1.0f) * 0.5f * (float)(Wl - 1);
    float fx = floorf(ix), fy = floorf(iy);
    float wx = ix - fx, wy = iy - fy;
    int x0 = (int)fx, y0 = (int)fy;
    int x1 = min(max(x0 + 1, 0), Wl - 1), y1 = min(max(y0 + 1, 0), Wl - 1);
    x0 = min(max(x0, 0), Wl - 1); y0 = min(max(y0, 0), Wl - 1);
    const u16* base = (lv == 0) ? B1 : (lv == 1) ? B2 : (lv == 2) ? B3 : B4;
    const u16* b00 = base + (y0 * Wl + x0) * 192;
    const u16* b01 = base + (y0 * Wl + x1) * 192;
    const u16* b10 = base + (y1 * Wl + x0) * 192;
    const u16* b11 = base + (y1 * Wl + x1) * 192;
    float w00 = (1.0f - wx) * (1.0f - wy), w01 = wx * (1.0f - wy);
    float w10 = (1.0f - wx) * wy,          w11 = wx * wy;
    u16* dstp = xt + p * 808 + lv * 192;
    int cph = (c4b + lv) & 3;
    int cc = cph * 8;
    u32x4 q00 = *(const u32x4*)(b00 + cc);
    u32x4 q01 = *(const u32x4*)(b01 + cc);
    u32x4 q10 = *(const u32x4*)(b10 + cc);
    u32x4 q11 = *(const u32x4*)(b11 + cc);
#pragma unroll
    for (int i = 0; i < 5; ++i) {
      int cn = cc + 32;                // next chunk: +4 channels*8
      u32x4 n00 = *(const u32x4*)(b00 + cn);
      u32x4 n01 = *(const u32x4*)(b01 + cn);
      u32x4 n10 = *(const u32x4*)(b10 + cn);
      u32x4 n11 = *(const u32x4*)(b11 + cn);
      *(u32x4*)(dstp + cc) = bilin4(q00, q01, q10, q11, w00, w01, w10, w11);
      cc = cn;
      q00 = n00; q01 = n01; q10 = n10; q11 = n11;
    }
    *(u32x4*)(dstp + cc) = bilin4(q00, q01, q10, q11, w00, w01, w10, w11);
  }
  __syncthreads();

  // ---- MFMA: each wave: 1 M-tile(16) x 3 N-tiles, 2-deep pipelined K-loop.
  // B loads hit the fragment-linear Wseed: one contiguous 1KiB burst/wave.
  const int lid = t & 63, wv = t >> 6;
  const int quad = lid >> 4, mrow = lid & 15;
  const int nt0 = wv * 3;

  f32x4 accS[3];
#pragma unroll
  for (int j = 0; j < 3; ++j) accS[j] = (f32x4)0.0f;

  const u16* ws = Wseed + (size_t)nt0 * 12800 + lid * 8;   // nt stride 25*512
  const u16* arow = xt + mrow * 808 + quad * 8;

  s16x8 a  = *(const s16x8*)(arow);
  s16x8 b0 = *(const s16x8*)(ws);
  s16x8 b1 = *(const s16x8*)(ws + 12800);
  s16x8 b2 = *(const s16x8*)(ws + 25600);
#pragma unroll 6
  for (int kc = 0; kc < 24; ++kc) {
    s16x8 an = *(const s16x8*)(arow + (kc + 1) * 32);
    const u16* wp = ws + (kc + 1) * 512;
    s16x8 b0n = *(const s16x8*)(wp);
    s16x8 b1n = *(const s16x8*)(wp + 12800);
    s16x8 b2n = *(const s16x8*)(wp + 25600);
    accS[0] = __builtin_amdgcn_mfma_f32_16x16x32_bf16(a, b0, accS[0], 0, 0, 0);
    accS[1] = __builtin_amdgcn_mfma_f32_16x16x32_bf16(a, b1, accS[1], 0, 0, 0);
    accS[2] = __builtin_amdgcn_mfma_f32_16x16x32_bf16(a, b2, accS[2], 0, 0, 0);
    a = an; b0 = b0n; b1 = b1n; b2 = b2n;
  }
  accS[0] = __builtin_amdgcn_mfma_f32_16x16x32_bf16(a, b0, accS[0], 0, 0, 0);
  accS[1] = __builtin_amdgcn_mfma_f32_16x16x32_bf16(a, b1, accS[1], 0, 0, 0);
  accS[2] = __builtin_amdgcn_mfma_f32_16x16x32_bf16(a, b2, accS[2], 0, 0, 0);

  // ---- pos: K=32 = PE chunk (kc==24 A-frag still in `a`); write
  // (C/D: col=lane&15, row=quad*4+reg)
#pragma unroll
  for (int j = 0; j < 3; ++j) {
    s16x8 bw = *(const s16x8*)(Wpos + (size_t)(nt0 + j) * 512 + lid * 8);
    f32x4 ap = (f32x4)0.0f;
    ap = __builtin_amdgcn_mfma_f32_16x16x32_bf16(a, bw, ap, 0, 0, 0);
    int n = (nt0 + j) * 16 + mrow;
    float pb = pos_b[n];
#pragma unroll
    for (int r = 0; r < 4; ++r)
      out_pos[(size_t)(gp0 + quad * 4 + r) * 192 + n] = ap[r] + pb;
  }

  __syncthreads();                       // all xt reads done; alias as preLN
  float* preLN = (float*)xt;             // [16][193]
#pragma unroll
  for (int j = 0; j < 3; ++j) {
    int n = (nt0 + j) * 16 + mrow;
    float sb = seed_b[n];
#pragma unroll
    for (int r = 0; r < 4; ++r)
      preLN[(quad * 4 + r) * 193 + n] = accS[j][r] + sb;
  }
  __syncthreads();

  // ---- LayerNorm stats: 16 threads per row
  {
    int r = t >> 4, g = t & 15;
    float s = 0.0f, sq = 0.0f;
#pragma unroll
    for (int i = 0; i < 12; ++i) {
      float v = preLN[r * 193 + g * 12 + i];
      s += v; sq += v * v;
    }
#pragma unroll
    for (int d = 8; d > 0; d >>= 1) {
      s += __shfl_down(s, d, 16);
      sq += __shfl_down(sq, d, 16);
    }
    if (g == 0) {
      float mu = s * (1.0f / 192.0f);
      float var = sq * (1.0f / 192.0f) - mu * mu;
      mu_s[r] = mu;
      rs_s[r] = 1.0f / sqrtf(var + 1e-5f);
    }
  }
  __syncthreads();

  // ---- normalized seed write, coalesced
  for (int i = 0; i < 12; ++i) {
    int e = i * 256 + t;
    int r = e / 192, n = e - r * 192;
    float v = (preLN[r * 193 + n] - mu_s[r]) * rs_s[r] * ln_g[n] + ln_b[n];
    out_seed[(size_t)(gp0 + r) * 192 + n] = v;
  }
}

extern "C" void kernel_launch(void* const* d_in, const int* in_sizes, int n_in,
                              void* d_out, int out_size, void* d_ws, size_t ws_size,
                              hipStream_t stream) {
  const float* coords  = (const float*)d_in[0];
  const float* L1      = (const float*)d_in[1];
  const float* L2      = (const float*)d_in[2];
  const float* L3      = (const float*)d_in[3];
  const float* L4      = (const float*)d_in[4];
  const float* Wseed_w = (const float*)d_in[5];
  const float* Wseed_b = (const float*)d_in[6];
  const float* ln_g    = (const float*)d_in[7];
  const float* ln_b    = (const float*)d_in[8];
  const float* Wpos_w  = (const float*)d_in[9];
  const float* Wpos_b  = (const float*)d_in[10];

  u16* T1  = (u16*)d_ws;
  u16* T2  = T1 + (size_t)8 * 16384 * 192;
  u16* T3  = T2 + (size_t)8 * 4096 * 192;
  u16* T4  = T3 + (size_t)8 * 1024 * 192;
  u16* Wsd = T4 + (size_t)8 * 256 * 192;
  u16* Wps = Wsd + 153600;

  prep_all<<<800, 512, 0, stream>>>(L1, L2, L3, L4, Wseed_w, Wpos_w,
                                    T1, T2, T3, T4, Wsd, Wps);

  float* out_seed = (float*)d_out;
  float* out_pos  = out_pos = out_seed + (size_t)32768 * 192;
  float* out_cg   = out_pos  + (size_t)32768 * 192;

  seed_main<<<2048, 256, 0, stream>>>(coords, T1, T2, T3, T4, Wsd, Wps,
                                      Wseed_b, ln_g, ln_b, Wpos_b,
                                      out_seed, out_pos, out_cg);
}

// Round 9
// 252.651 us; speedup vs baseline: 1.0603x; 1.0603x over previous
//
#include <hip/hip_runtime.h>
#include <hip/hip_bf16.h>
#include <stdint.h>

typedef unsigned short u16;
typedef short s16x8 __attribute__((ext_vector_type(8)));
typedef float f32x4 __attribute__((ext_vector_type(4)));
typedef uint32_t u32x4 __attribute__((ext_vector_type(4)));

__device__ __forceinline__ uint32_t pack_bf16(float lo, float hi) {
  float2 f; f.x = lo; f.y = hi;
  __hip_bfloat162 h = __float22bfloat162_rn(f);
  union { __hip_bfloat162 h; uint32_t u; } c; c.h = h;
  return c.u;
}
__device__ __forceinline__ u16 f2bf(float f) {
  union { float f; uint32_t u; } a; a.f = f;
  uint32_t u = a.u;
  return (u16)((u + 0x7fffu + ((u >> 16) & 1u)) >> 16);
}
__device__ __forceinline__ float bf2f(uint32_t hbits) {
  union { uint32_t u; float f; } a; a.u = hbits << 16;
  return a.f;
}

__device__ __forceinline__ u32x4 bilin4(u32x4 q00, u32x4 q01, u32x4 q10, u32x4 q11,
                                        float w00, float w01, float w10, float w11) {
  u32x4 o;
#pragma unroll
  for (int k = 0; k < 4; ++k) {
    float lo = bf2f(q00[k] & 0xffff) * w00 + bf2f(q01[k] & 0xffff) * w01 +
               bf2f(q10[k] & 0xffff) * w10 + bf2f(q11[k] & 0xffff) * w11;
    float hi = bf2f(q00[k] >> 16) * w00 + bf2f(q01[k] >> 16) * w01 +
               bf2f(q10[k] >> 16) * w10 + bf2f(q11[k] >> 16) * w11;
    o[k] = pack_bf16(lo, hi);
  }
  return o;
}

// ---------------------------------------------------------------- fused prep
// Macro-tile transpose: 128 hw x 192 c per block, 512 threads, 48 KB LDS.
// VERIFIED-BEST variant (round 5: 253.7 us total; prep 63-68 us). Eight
// structural families (segments 256B-1KB, write contiguity 96B-48KB,
// occupancy 43-62%, XCD swizzle, DMA staging, counted-vmcnt dbuf pipeline)
// all land at 63-75 us / ~2 TB/s HBM -- this op's mixed-pattern fabric
// ceiling (~3.1 TB/s combined, ~half the pure-copy 6.3 TB/s). Notable:
// 96B write segments ADD ~9MB HBM write traffic vs 192B (round-8 finding);
// keep u32x4 (16B/lane, 384B-contig/row) stores.
// blocks [0,1024): L1; [1024,1280): L2; [1280,1344): L3; [1344,1360): L4;
// [1360,1392): W convert+swizzle (grid-stride).
//
// W layout: Wseed/Wpos in MFMA-fragment-linear order:
//   dWs[((nt*25 + kc)*64 + lid)*8 + e] = W[nt*16 + (lid&15)][kc*32 + (lid>>4)*8 + e]
__global__ __launch_bounds__(512, 4) void prep_all(
    const float* __restrict__ L1, const float* __restrict__ L2,
    const float* __restrict__ L3, const float* __restrict__ L4,
    const float* __restrict__ ws_w, const float* __restrict__ wp_w,
    u16* __restrict__ T1, u16* __restrict__ T2,
    u16* __restrict__ T3, u16* __restrict__ T4,
    u16* __restrict__ dWs, u16* __restrict__ dWp) {
  const int bid = blockIdx.x;
  const int t = threadIdx.x;

  if (bid >= 1360) {  // ---- W convert: 159744 f32 total as 39936 float4s
    int t0 = (bid - 1360) * 512 + t;
    for (int i = t0; i < 39936; i += 16384) {
      if (i < 38400) {
        int e4 = 4 * i;                 // element index in Wseed (n*800 + k)
        int n = e4 / 800;
        int k = e4 - n * 800;
        f32x4 v = *(const f32x4*)(ws_w + e4);
        int nt = n >> 4, mrow = n & 15;
        int kc = k >> 5, quad = (k >> 3) & 3, e0 = k & 7;  // e0 in {0,4}
        int dst = ((nt * 25 + kc) * 64 + (quad * 16 + mrow)) * 8 + e0;
        uint2 o;
        o.x = pack_bf16(v.x, v.y);
        o.y = pack_bf16(v.z, v.w);
        *(uint2*)(dWs + dst) = o;
      } else {
        int j = i - 38400;
        int e4 = 4 * j;                 // element index in Wpos (n*32 + k)
        int n = e4 >> 5, k = e4 & 31;
        f32x4 v = *(const f32x4*)(wp_w + e4);
        int nt = n >> 4, mrow = n & 15;
        int quad = k >> 3, e0 = k & 7;
        int dst = (nt * 64 + (quad * 16 + mrow)) * 8 + e0;
        uint2 o;
        o.x = pack_bf16(v.x, v.y);
        o.y = pack_bf16(v.z, v.w);
        *(uint2*)(dWp + dst) = o;
      }
    }
    return;
  }

  const float* src; u16* dst; int HW, tiles, rel;
  if (bid < 1024)      { src = L1; dst = T1; HW = 16384; tiles = 128; rel = bid; }
  else if (bid < 1280) { src = L2; dst = T2; HW = 4096;  tiles = 32;  rel = bid - 1024; }
  else if (bid < 1344) { src = L3; dst = T3; HW = 1024;  tiles = 8;   rel = bid - 1280; }
  else                 { src = L4; dst = T4; HW = 256;   tiles = 2;   rel = bid - 1344; }
  const int b = rel / tiles, hw0 = (rel % tiles) * 128;

  // [96 c2][128 hw] u32, XOR-swizzled within row: col' = col ^ swz(c2)
  __shared__ uint32_t tileD[96 * 128];   // 48 KB
  const float* sb = src + (size_t)b * 192 * HW + hw0;

  // ---- load + pack + LDS write: 6 iters, 2x 512B-segment f32x4 loads each
#pragma unroll
  for (int i = 0; i < 6; ++i) {
    int idx = i * 512 + t;                 // 3072 = 96 c2 x 32 hw4
    int c2 = idx >> 5, hw4 = idx & 31;     // lanes: consecutive hw4 -> 512B rows
    f32x4 a = *(const f32x4*)(sb + (size_t)(2 * c2) * HW + hw4 * 4);
    f32x4 c = *(const f32x4*)(sb + (size_t)(2 * c2 + 1) * HW + hw4 * 4);
    int swz = ((c2 >> 2) & 7) << 2;
    u32x4 w;
    w[0] = pack_bf16(a.x, c.x);
    w[1] = pack_bf16(a.y, c.y);
    w[2] = pack_bf16(a.z, c.z);
    w[3] = pack_bf16(a.w, c.w);
    *(u32x4*)&tileD[c2 * 128 + ((hw4 * 4) ^ swz)] = w;   // ds_write_b128
  }
  __syncthreads();

  // ---- store phase: 16B per lane, 384B contiguous per hw row, 48 KB/block
#pragma unroll
  for (int i = 0; i < 6; ++i) {
    int e = i * 512 + t;                   // 3072 = 128 hw x 24 q
    int hw = e / 24, q = e - hw * 24;      // lanes: consecutive q -> coalesced 16B
    u32x4 v;
#pragma unroll
    for (int k = 0; k < 4; ++k) {
      int c2 = q * 4 + k;
      int swz = ((c2 >> 2) & 7) << 2;      // = (q&7)<<2
      v[k] = tileD[c2 * 128 + (hw ^ swz)];
    }
    uint32_t* d = (uint32_t*)(dst + ((size_t)b * HW + hw0) * 192);
    *(u32x4*)(d + hw * 96 + q * 4) = v;
  }
}

// ---------------------------------------------------------------- main fused
// 16 points/block, 2048 blocks, 256 threads (4 waves). xt [16][808] bf16 in
// LDS (25.9 KB -> 6 blocks/CU, 24 waves/CU). launch_bounds(256,6) caps VGPR
// at 85 so the deeper pipelines below don't cost occupancy.
__global__ __launch_bounds__(256, 6) void seed_main(
    const float* __restrict__ coords,
    const u16* __restrict__ T1, const u16* __restrict__ T2,
    const u16* __restrict__ T3, const u16* __restrict__ T4,
    const u16* __restrict__ Wseed, const u16* __restrict__ Wpos,
    const float* __restrict__ seed_b, const float* __restrict__ ln_g,
    const float* __restrict__ ln_b, const float* __restrict__ pos_b,
    float* __restrict__ out_seed, float* __restrict__ out_pos,
    float* __restrict__ out_cg) {

  __shared__ __align__(16) u16 xt[16 * 808];   // aliased later as preLN f32 [16][193]
  __shared__ float mu_s[16], rs_s[16];

  const int t = threadIdx.x;
  const int gp0 = blockIdx.x * 16;
  const int b = gp0 >> 12;

  // ---- center grid out
  if (t < 32) {
    int p = t >> 1, xy = t & 1;
    float c = coords[(gp0 + p) * 2 + xy];
    out_cg[(gp0 + p) * 2 + xy] = c * (2.0f / 511.0f) - 1.0f;
  }
  // ---- PE: 16 pts x 32 vals -> xt cols 768..799
  for (int i = 0; i < 2; ++i) {
    int e = i * 256 + t;
    int p = e >> 5, j = e & 31;
    float c = coords[(gp0 + p) * 2 + ((j >> 4) & 1)] * (1.0f / 512.0f);
    float v = c * (float)(1 << (j & 7));
    float a = (v - floorf(v)) * 6.283185307179586f;
    float r = (j & 8) ? __cosf(a) : __sinf(a);
    xt[p * 808 + 768 + j] = f2bf(r);
  }

  // ---- gather: thread owns one (p,lv); 6 chunks of 8 channels (16 B loads),
  // 2-deep software pipeline (prefetch chunk i+1 while interpolating chunk i).
  // Chunk phase rotated by lv so the 4 lv-lanes of a (p,c4b) group write
  // distinct LDS bank quads (kills the 4-way ds_write conflict).
  {
    const u16* B1 = T1 + (size_t)b * 16384 * 192;
    const u16* B2 = T2 + (size_t)b * 4096 * 192;
    const u16* B3 = T3 + (size_t)b * 1024 * 192;
    const u16* B4 = T4 + (size_t)b * 256 * 192;
    int plv = t >> 2;                  // [0,64)
    int lv = plv & 3, p = plv >> 2;
    int c4b = t & 3;                   // chunk phase
    float cx = coords[(gp0 + p) * 2 + 0];
    float cy = coords[(gp0 + p) * 2 + 1];
    float gx = cx * (2.0f / 511.0f) - 1.0f;
    float gy = cy * (2.0f / 511.0f) - 1.0f;
    int Wl = 128 >> lv;
    float ix = (gx + 1.0f) * 0.5f * (float)(Wl - 1);
    float iy = (gy + 1.0f) * 0.5f * (float)(Wl - 1);
    float fx = floorf(ix), fy = floorf(iy);
    float wx = ix - fx, wy = iy - fy;
    int x0 = (int)fx, y0 = (int)fy;
    int x1 = min(max(x0 + 1, 0), Wl - 1), y1 = min(max(y0 + 1, 0), Wl - 1);
    x0 = min(max(x0, 0), Wl - 1); y0 = min(max(y0, 0), Wl - 1);
    const u16* base = (lv == 0) ? B1 : (lv == 1) ? B2 : (lv == 2) ? B3 : B4;
    const u16* b00 = base + (y0 * Wl + x0) * 192;
    const u16* b01 = base + (y0 * Wl + x1) * 192;
    const u16* b10 = base + (y1 * Wl + x0) * 192;
    const u16* b11 = base + (y1 * Wl + x1) * 192;
    float w00 = (1.0f - wx) * (1.0f - wy), w01 = wx * (1.0f - wy);
    float w10 = (1.0f - wx) * wy,          w11 = wx * wy;
    u16* dstp = xt + p * 808 + lv * 192;
    int cph = (c4b + lv) & 3;
    int cc = cph * 8;
    u32x4 q00 = *(const u32x4*)(b00 + cc);
    u32x4 q01 = *(const u32x4*)(b01 + cc);
    u32x4 q10 = *(const u32x4*)(b10 + cc);
    u32x4 q11 = *(const u32x4*)(b11 + cc);
#pragma unroll
    for (int i = 0; i < 5; ++i) {
      int cn = cc + 32;                // next chunk: +4 channels*8
      u32x4 n00 = *(const u32x4*)(b00 + cn);
      u32x4 n01 = *(const u32x4*)(b01 + cn);
      u32x4 n10 = *(const u32x4*)(b10 + cn);
      u32x4 n11 = *(const u32x4*)(b11 + cn);
      *(u32x4*)(dstp + cc) = bilin4(q00, q01, q10, q11, w00, w01, w10, w11);
      cc = cn;
      q00 = n00; q01 = n01; q10 = n10; q11 = n11;
    }
    *(u32x4*)(dstp + cc) = bilin4(q00, q01, q10, q11, w00, w01, w10, w11);
  }
  __syncthreads();

  // ---- MFMA: each wave: 1 M-tile(16) x 3 N-tiles, 2-deep pipelined K-loop.
  // B loads hit the fragment-linear Wseed: one contiguous 1KiB burst/wave.
  const int lid = t & 63, wv = t >> 6;
  const int quad = lid >> 4, mrow = lid & 15;
  const int nt0 = wv * 3;

  f32x4 accS[3];
#pragma unroll
  for (int j = 0; j < 3; ++j) accS[j] = (f32x4)0.0f;

  const u16* ws = Wseed + (size_t)nt0 * 12800 + lid * 8;   // nt stride 25*512
  const u16* arow = xt + mrow * 808 + quad * 8;

  s16x8 a  = *(const s16x8*)(arow);
  s16x8 b0 = *(const s16x8*)(ws);
  s16x8 b1 = *(const s16x8*)(ws + 12800);
  s16x8 b2 = *(const s16x8*)(ws + 25600);
#pragma unroll 6
  for (int kc = 0; kc < 24; ++kc) {
    s16x8 an = *(const s16x8*)(arow + (kc + 1) * 32);
    const u16* wp = ws + (kc + 1) * 512;
    s16x8 b0n = *(const s16x8*)(wp);
    s16x8 b1n = *(const s16x8*)(wp + 12800);
    s16x8 b2n = *(const s16x8*)(wp + 25600);
    accS[0] = __builtin_amdgcn_mfma_f32_16x16x32_bf16(a, b0, accS[0], 0, 0, 0);
    accS[1] = __builtin_amdgcn_mfma_f32_16x16x32_bf16(a, b1, accS[1], 0, 0, 0);
    accS[2] = __builtin_amdgcn_mfma_f32_16x16x32_bf16(a, b2, accS[2], 0, 0, 0);
    a = an; b0 = b0n; b1 = b1n; b2 = b2n;
  }
  accS[0] = __builtin_amdgcn_mfma_f32_16x16x32_bf16(a, b0, accS[0], 0, 0, 0);
  accS[1] = __builtin_amdgcn_mfma_f32_16x16x32_bf16(a, b1, accS[1], 0, 0, 0);
  accS[2] = __builtin_amdgcn_mfma_f32_16x16x32_bf16(a, b2, accS[2], 0, 0, 0);

  // ---- pos: K=32 = PE chunk (kc==24 A-frag still in `a`); write
  // (C/D: col=lane&15, row=quad*4+reg)
#pragma unroll
  for (int j = 0; j < 3; ++j) {
    s16x8 bw = *(const s16x8*)(Wpos + (size_t)(nt0 + j) * 512 + lid * 8);
    f32x4 ap = (f32x4)0.0f;
    ap = __builtin_amdgcn_mfma_f32_16x16x32_bf16(a, bw, ap, 0, 0, 0);
    int n = (nt0 + j) * 16 + mrow;
    float pb = pos_b[n];
#pragma unroll
    for (int r = 0; r < 4; ++r)
      out_pos[(size_t)(gp0 + quad * 4 + r) * 192 + n] = ap[r] + pb;
  }

  __syncthreads();                       // all xt reads done; alias as preLN
  float* preLN = (float*)xt;             // [16][193]
#pragma unroll
  for (int j = 0; j < 3; ++j) {
    int n = (nt0 + j) * 16 + mrow;
    float sb = seed_b[n];
#pragma unroll
    for (int r = 0; r < 4; ++r)
      preLN[(quad * 4 + r) * 193 + n] = accS[j][r] + sb;
  }
  __syncthreads();

  // ---- LayerNorm stats: 16 threads per row
  {
    int r = t >> 4, g = t & 15;
    float s = 0.0f, sq = 0.0f;
#pragma unroll
    for (int i = 0; i < 12; ++i) {
      float v = preLN[r * 193 + g * 12 + i];
      s += v; sq += v * v;
    }
#pragma unroll
    for (int d = 8; d > 0; d >>= 1) {
      s += __shfl_down(s, d, 16);
      sq += __shfl_down(sq, d, 16);
    }
    if (g == 0) {
      float mu = s * (1.0f / 192.0f);
      float var = sq * (1.0f / 192.0f) - mu * mu;
      mu_s[r] = mu;
      rs_s[r] = 1.0f / sqrtf(var + 1e-5f);
    }
  }
  __syncthreads();

  // ---- normalized seed write, coalesced
  for (int i = 0; i < 12; ++i) {
    int e = i * 256 + t;
    int r = e / 192, n = e - r * 192;
    float v = (preLN[r * 193 + n] - mu_s[r]) * rs_s[r] * ln_g[n] + ln_b[n];
    out_seed[(size_t)(gp0 + r) * 192 + n] = v;
  }
}

extern "C" void kernel_launch(void* const* d_in, const int* in_sizes, int n_in,
                              void* d_out, int out_size, void* d_ws, size_t ws_size,
                              hipStream_t stream) {
  const float* coords  = (const float*)d_in[0];
  const float* L1      = (const float*)d_in[1];
  const float* L2      = (const float*)d_in[2];
  const float* L3      = (const float*)d_in[3];
  const float* L4      = (const float*)d_in[4];
  const float* Wseed_w = (const float*)d_in[5];
  const float* Wseed_b = (const float*)d_in[6];
  const float* ln_g    = (const float*)d_in[7];
  const float* ln_b    = (const float*)d_in[8];
  const float* Wpos_w  = (const float*)d_in[9];
  const float* Wpos_b  = (const float*)d_in[10];

  u16* T1  = (u16*)d_ws;
  u16* T2  = T1 + (size_t)8 * 16384 * 192;
  u16* T3  = T2 + (size_t)8 * 4096 * 192;
  u16* T4  = T3 + (size_t)8 * 1024 * 192;
  u16* Wsd = T4 + (size_t)8 * 256 * 192;
  u16* Wps = Wsd + 153600;

  prep_all<<<1392, 512, 0, stream>>>(L1, L2, L3, L4, Wseed_w, Wpos_w,
                                     T1, T2, T3, T4, Wsd, Wps);

  float* out_seed = (float*)d_out;
  float* out_pos  = out_seed + (size_t)32768 * 192;
  float* out_cg   = out_pos  + (size_t)32768 * 192;

  seed_main<<<2048, 256, 0, stream>>>(coords, T1, T2, T3, T4, Wsd, Wps,
                                      Wseed_b, ln_g, ln_b, Wpos_b,
                                      out_seed, out_pos, out_cg);
}